// Round 8
// baseline (475.703 us; speedup 1.0000x reference)
//
#include <hip/hip_runtime.h>
#include <hip/hip_fp16.h>
#include <cstdint>
#include <cstddef>

#define E_HID 256
#define R_HID 128
#define NREL  1000
#define EPSF  1e-16f
#define CH_BITS 11
#define NCH   25                  // ceil(50000/2048) node chunks
#define NBIN  (NREL * NCH)        // 25000 bins per list (rel-major, chunk-minor)
#define G5    (2 * NREL)          // k5 blocks: one per (list, rel)

typedef _Float16 f16x8 __attribute__((ext_vector_type(8)));
typedef float f32x4 __attribute__((ext_vector_type(4)));

struct alignas(16) h8 { __half2 a, b, c, d; };

// ================= K0: WcT[c][k] = fp16 of (c<128 ? Wh[k][c] : Wt[k][c-128])
__global__ __launch_bounds__(256) void k0_prep(
    const float* __restrict__ Wh, const float* __restrict__ Wt,
    __half* __restrict__ WcT)
{
  const int k = blockIdx.x;
  const int c = threadIdx.x;
  const float v = (c < R_HID) ? Wh[(size_t)k * R_HID + c]
                              : Wt[(size_t)k * R_HID + (c - R_HID)];
  WcT[(size_t)c * E_HID + k] = __float2half(v);
}

// ================= K1: MFMA fp16 GEMM (validated R3+) =======================
__global__ __launch_bounds__(256) void k1_gemm(
    const float* __restrict__ xe, const __half* __restrict__ WcT,
    const float* __restrict__ ah1, const float* __restrict__ ah2,
    const float* __restrict__ at1, const float* __restrict__ at2,
    __half* __restrict__ xhH, __half* __restrict__ xtH,
    float* __restrict__ sh1, float* __restrict__ sh2,
    float* __restrict__ st1, float* __restrict__ st2, int N)
{
  __shared__ __half As[128 * 32];
  __shared__ __half Bs[128 * 32];
  __shared__ float sA[2][128];
  __shared__ float sB[2][128];

  const int tid  = threadIdx.x;
  const int lane = tid & 63;
  const int wid  = tid >> 6;
  const int wr = wid >> 1, wc = wid & 1;
  const int nbm = (N + 127) >> 7;
  const int mb = blockIdx.x % nbm;
  const int cb = blockIdx.x / nbm;
  const int n0 = mb * 128;

  f32x4 acc[4][4];
  #pragma unroll
  for (int m = 0; m < 4; ++m)
    #pragma unroll
    for (int n = 0; n < 4; ++n) acc[m][n] = (f32x4){0.f, 0.f, 0.f, 0.f};

  const int arow = tid >> 1, ah = tid & 1;
  const bool aok = (n0 + arow) < N;
  const float*  xsrc = xe + (size_t)(n0 + arow) * E_HID + ah * 16;
  const __half* bsrc = WcT + ((size_t)(cb * 128 + arow) << 8) + ah * 16;
  __half* Aw = &As[arow * 32 + ah * 16];
  __half* Bw = &Bs[arow * 32 + ah * 16];

  const int fr = lane & 15, fq = lane >> 4;

  for (int kt = 0; kt < 8; ++kt) {
    __syncthreads();
    float4 v0 = make_float4(0,0,0,0), v1 = v0, v2 = v0, v3 = v0;
    if (aok) {
      const float* s = xsrc + kt * 32;
      v0 = *(const float4*)(s);     v1 = *(const float4*)(s + 4);
      v2 = *(const float4*)(s + 8); v3 = *(const float4*)(s + 12);
    }
    h8 p0, p1;
    p0.a = __floats2half2_rn(v0.x, v0.y); p0.b = __floats2half2_rn(v0.z, v0.w);
    p0.c = __floats2half2_rn(v1.x, v1.y); p0.d = __floats2half2_rn(v1.z, v1.w);
    p1.a = __floats2half2_rn(v2.x, v2.y); p1.b = __floats2half2_rn(v2.z, v2.w);
    p1.c = __floats2half2_rn(v3.x, v3.y); p1.d = __floats2half2_rn(v3.z, v3.w);
    *(h8*)(Aw) = p0; *(h8*)(Aw + 8) = p1;
    float4 b0 = *(const float4*)(bsrc + kt * 32);
    float4 b1 = *(const float4*)(bsrc + kt * 32 + 8);
    *(float4*)(Bw) = b0; *(float4*)(Bw + 8) = b1;
    __syncthreads();
    f16x8 aF[4], bF[4];
    #pragma unroll
    for (int m = 0; m < 4; ++m)
      aF[m] = *(const f16x8*)&As[(wr * 64 + m * 16 + fr) * 32 + fq * 8];
    #pragma unroll
    for (int n = 0; n < 4; ++n)
      bF[n] = *(const f16x8*)&Bs[(wc * 64 + n * 16 + fr) * 32 + fq * 8];
    #pragma unroll
    for (int m = 0; m < 4; ++m)
      #pragma unroll
      for (int n = 0; n < 4; ++n)
        acc[m][n] = __builtin_amdgcn_mfma_f32_16x16x32_f16(aF[m], bF[n], acc[m][n], 0, 0, 0);
  }

  __half* dst = (cb == 0) ? xhH : xtH;
  #pragma unroll
  for (int m = 0; m < 4; ++m) {
    const int rl0 = wr * 64 + m * 16 + fq * 4;
    #pragma unroll
    for (int r = 0; r < 4; ++r) {
      const int node = n0 + rl0 + r;
      if (node < N) {
        #pragma unroll
        for (int n = 0; n < 4; ++n)
          dst[(size_t)node * R_HID + wc * 64 + n * 16 + fr] = __float2half(acc[m][n][r]);
      }
    }
  }

  const float* aV1 = (cb == 0) ? ah1 : ah2;
  const float* aV2 = (cb == 0) ? at1 : at2;
  float avA[4], avB[4];
  #pragma unroll
  for (int n = 0; n < 4; ++n) {
    avA[n] = aV1[wc * 64 + n * 16 + fr];
    avB[n] = aV2[wc * 64 + n * 16 + fr];
  }
  #pragma unroll
  for (int m = 0; m < 4; ++m)
    #pragma unroll
    for (int r = 0; r < 4; ++r) {
      float vA = acc[m][0][r]*avA[0] + acc[m][1][r]*avA[1]
               + acc[m][2][r]*avA[2] + acc[m][3][r]*avA[3];
      float vB = acc[m][0][r]*avB[0] + acc[m][1][r]*avB[1]
               + acc[m][2][r]*avB[2] + acc[m][3][r]*avB[3];
      #pragma unroll
      for (int ofs = 1; ofs < 16; ofs <<= 1) {
        vA += __shfl_xor(vA, ofs, 16);
        vB += __shfl_xor(vB, ofs, 16);
      }
      if (fr == 0) {
        const int rl = wr * 64 + m * 16 + fq * 4 + r;
        sA[wc][rl] = vA;
        sB[wc][rl] = vB;
      }
    }
  __syncthreads();
  if (tid < 128 && n0 + tid < N) {
    float* o1 = (cb == 0) ? sh1 : sh2;
    float* o2 = (cb == 0) ? st1 : st2;
    o1[n0 + tid] = sA[0][tid] + sA[1][tid];
    o2[n0 + tid] = sB[0][tid] + sB[1][tid];
  }
}

// ================= K2: global-atomic histograms, (rel,chunk) bins ===========
// 50000 counters, mean ~64/ctr -> L2 atomics pipeline fine (R3-proven class).
__global__ __launch_bounds__(256) void k2_hist(
    const int* __restrict__ ei, const int* __restrict__ rel,
    unsigned* __restrict__ cntH, unsigned* __restrict__ cntT, int E)
{
  for (int i = blockIdx.x * 256 + threadIdx.x; i < E; i += gridDim.x * 256) {
    const int r = rel[i];
    atomicAdd(cntH + r * NCH + (ei[i] >> CH_BITS), 1u);
    atomicAdd(cntT + r * NCH + (ei[E + i] >> CH_BITS), 1u);
  }
}

// ================= K3: carry-scan of 25000 bin totals (one block per list) ==
__global__ __launch_bounds__(1024) void k3_scan(
    const unsigned* __restrict__ cnt, unsigned* __restrict__ offs,
    unsigned* __restrict__ cur)
{
  __shared__ unsigned s[1024];
  const int list = blockIdx.x;
  const unsigned* c = cnt + (size_t)list * NBIN;
  unsigned* o = offs + (size_t)list * (NBIN + 1);
  unsigned* u = cur  + (size_t)list * NBIN;
  const int t = threadIdx.x;
  unsigned carry = 0u;
  for (int base = 0; base < NBIN; base += 1024) {
    const int idx = base + t;
    const unsigned v = (idx < NBIN) ? c[idx] : 0u;
    s[t] = v;
    __syncthreads();
    for (int ofs = 1; ofs < 1024; ofs <<= 1) {
      const unsigned add = (t >= ofs) ? s[t - ofs] : 0u;
      __syncthreads();
      s[t] += add;
      __syncthreads();
    }
    if (idx < NBIN) {
      const unsigned e = carry + s[t] - v;
      o[idx] = e;
      u[idx] = e;
    }
    carry += s[1023];
    __syncthreads();
  }
  if (t == 0) o[NBIN] = carry;
}

// ================= K4: scatter via global position atomics ==================
// meta = { node (32b), w as f32 bits }
__global__ __launch_bounds__(256) void k4_scatter(
    const int* __restrict__ ei, const int* __restrict__ rel,
    const float* __restrict__ sh1, const float* __restrict__ sh2,
    const float* __restrict__ st1, const float* __restrict__ st2,
    unsigned* __restrict__ curH, unsigned* __restrict__ curT,
    uint2* __restrict__ metaH, uint2* __restrict__ metaT, int E)
{
  for (int i = blockIdx.x * 256 + threadIdx.x; i < E; i += gridDim.x * 256) {
    const int h = ei[i], t = ei[E + i], r = rel[i];
    const float e1 = sh1[h] + sh2[t];
    const float e2 = st1[h] + st2[t];
    const float l1 = e1 >= 0.f ? e1 : 0.01f * e1;
    const float l2 = e2 >= 0.f ? e2 : 0.01f * e2;
    const float w1 = expf(l1);
    const float w2 = expf(l2);
    const unsigned pH = atomicAdd(curH + r * NCH + (h >> CH_BITS), 1u);
    metaH[pH] = make_uint2((unsigned)h, __float_as_uint(w1));
    const unsigned pT = atomicAdd(curT + r * NCH + (t >> CH_BITS), 1u);
    metaT[pT] = make_uint2((unsigned)t, __float_as_uint(w2));
  }
}

// ================= K5: chunk-phased register gather-reduce ==================
// block = (list, rel); 4 waves split each chunk-bin's edges; ALL blocks sweep
// chunks 0..24 in the same order -> chip-wide active set ~1-3 MB -> L2 hits.
// Register accumulation across the whole sweep; single flush at the end.
__global__ __launch_bounds__(256) void k5_reduce(
    const unsigned* __restrict__ offs,
    const uint2* __restrict__ metaH, const uint2* __restrict__ metaT,
    const __half* __restrict__ xhH, const __half* __restrict__ xtH,
    float* __restrict__ part, float* __restrict__ partS)
{
  __shared__ float accW[4][130];
  __shared__ float accSw[4];
  const int tid  = threadIdx.x;
  const int lane = tid & 63;
  const int wv   = __builtin_amdgcn_readfirstlane(tid >> 6);
  const int bid  = blockIdx.x;
  const int list = bid / NREL;
  const int r    = bid % NREL;

  const unsigned* o    = offs + (size_t)list * (NBIN + 1);
  const uint2*    meta = list ? metaT : metaH;
  const __half*   xsrc = list ? xtH   : xhH;
  const __half*   xl   = xsrc + 2 * lane;

  float a0 = 0.f, a1 = 0.f, sw = 0.f;

  for (int c = 0; c < NCH; ++c) {
    const unsigned s0 = o[r * NCH + c];
    const unsigned s1 = o[r * NCH + c + 1];
    const unsigned len = s1 - s0;
    unsigned p        = s0 + ((len * (unsigned)wv) >> 2);
    const unsigned pe = s0 + ((len * (unsigned)(wv + 1)) >> 2);

    for (; p + 4 <= pe; p += 4) {
      const uint2 m0 = meta[p],     m1 = meta[p + 1];
      const uint2 m2 = meta[p + 2], m3 = meta[p + 3];
      const float2 f0 = __half22float2(*(const __half2*)(xl + ((size_t)m0.x << 7)));
      const float2 f1 = __half22float2(*(const __half2*)(xl + ((size_t)m1.x << 7)));
      const float2 f2 = __half22float2(*(const __half2*)(xl + ((size_t)m2.x << 7)));
      const float2 f3 = __half22float2(*(const __half2*)(xl + ((size_t)m3.x << 7)));
      const float w0 = __uint_as_float(m0.y), w1 = __uint_as_float(m1.y);
      const float w2 = __uint_as_float(m2.y), w3 = __uint_as_float(m3.y);
      a0 += w0 * f0.x; a1 += w0 * f0.y; sw += w0;
      a0 += w1 * f1.x; a1 += w1 * f1.y; sw += w1;
      a0 += w2 * f2.x; a1 += w2 * f2.y; sw += w2;
      a0 += w3 * f3.x; a1 += w3 * f3.y; sw += w3;
    }
    for (; p < pe; ++p) {
      const uint2 m = meta[p];
      const float2 f = __half22float2(*(const __half2*)(xl + ((size_t)m.x << 7)));
      const float w = __uint_as_float(m.y);
      a0 += w * f.x; a1 += w * f.y; sw += w;
    }
  }

  accW[wv][2 * lane]     = a0;
  accW[wv][2 * lane + 1] = a1;
  if (lane == 0) accSw[wv] = sw;
  __syncthreads();
  if (tid < 128) {
    part[(size_t)bid * R_HID + tid] =
        accW[0][tid] + accW[1][tid] + accW[2][tid] + accW[3][tid];
  }
  if (tid == 0)
    partS[bid] = accSw[0] + accSw[1] + accSw[2] + accSw[3];
}

// ================= K6: finalize =============================================
__global__ __launch_bounds__(128) void k6_final(
    const float* __restrict__ part, const float* __restrict__ partS,
    float* __restrict__ out)
{
  const int r = blockIdx.x;
  const int d = threadIdx.x;
  const float oh = part[(size_t)r * R_HID + d];
  const float ot = part[(size_t)(NREL + r) * R_HID + d];
  const float s1 = partS[r];
  const float s2 = partS[NREL + r];
  out[r * R_HID + d] = oh / (s1 + EPSF) + ot / (s2 + EPSF);
}

extern "C" void kernel_launch(void* const* d_in, const int* in_sizes, int n_in,
                              void* d_out, int out_size, void* d_ws, size_t ws_size,
                              hipStream_t stream) {
  const float* xe  = (const float*)d_in[0];
  const int*   ei  = (const int*)d_in[1];
  const int*   rel = (const int*)d_in[2];
  const float* Wh  = (const float*)d_in[3];
  const float* Wt  = (const float*)d_in[4];
  const float* ah1 = (const float*)d_in[5];
  const float* ah2 = (const float*)d_in[6];
  const float* at1 = (const float*)d_in[7];
  const float* at2 = (const float*)d_in[8];
  const int N = in_sizes[0] / E_HID;
  const int E = in_sizes[2];

  char* w = (char*)d_ws;
  size_t o = 0;
  auto alloc = [&](size_t bytes) -> void* {
    void* p = w + o;
    o = (o + bytes + 255) & ~(size_t)255;
    return p;
  };
  __half* WcT = (__half*)alloc((size_t)E_HID * E_HID * 2);
  __half* xhH = (__half*)alloc((size_t)N * R_HID * 2);
  __half* xtH = (__half*)alloc((size_t)N * R_HID * 2);
  float* sh1 = (float*)alloc((size_t)N * 4);
  float* sh2 = (float*)alloc((size_t)N * 4);
  float* st1 = (float*)alloc((size_t)N * 4);
  float* st2 = (float*)alloc((size_t)N * 4);
  uint2* metaH = (uint2*)alloc((size_t)E * 8);
  uint2* metaT = (uint2*)alloc((size_t)E * 8);
  unsigned* cur  = (unsigned*)alloc((size_t)2 * NBIN * 4);
  unsigned* offs = (unsigned*)alloc((size_t)2 * (NBIN + 1) * 4);
  float* part  = (float*)alloc((size_t)G5 * R_HID * 4);
  float* partS = (float*)alloc((size_t)G5 * 4);
  const size_t zstart = o;
  unsigned* cnt  = (unsigned*)alloc((size_t)2 * NBIN * 4);
  const size_t zbytes = o - zstart;

  hipMemsetAsync(w + zstart, 0, zbytes, stream);

  const int nbm = (N + 127) >> 7;
  k0_prep<<<E_HID, 256, 0, stream>>>(Wh, Wt, WcT);
  k1_gemm<<<nbm * 2, 256, 0, stream>>>(xe, WcT, ah1, ah2, at1, at2,
                                       xhH, xtH, sh1, sh2, st1, st2, N);
  k2_hist<<<1024, 256, 0, stream>>>(ei, rel, cnt, cnt + NBIN, E);
  k3_scan<<<2, 1024, 0, stream>>>(cnt, offs, cur);
  k4_scatter<<<1024, 256, 0, stream>>>(ei, rel, sh1, sh2, st1, st2,
                                       cur, cur + NBIN, metaH, metaT, E);
  k5_reduce<<<G5, 256, 0, stream>>>(offs, metaH, metaT, xhH, xtH, part, partS);
  k6_final<<<NREL, 128, 0, stream>>>(part, partS, (float*)d_out);
}

// Round 9
// 473.982 us; speedup vs baseline: 1.0036x; 1.0036x over previous
//
#include <hip/hip_runtime.h>
#include <hip/hip_fp16.h>
#include <cstdint>
#include <cstddef>

#define E_HID 256
#define R_HID 128
#define NREL  1000
#define EPSF  1e-16f
#define CH_BITS 11
#define NCH   25                  // ceil(50000/2048) node chunks
#define NBIN  (NREL * NCH)        // 25000 bins per list (rel-major, chunk-minor)
#define SPLIT 2                   // chunk-parity split
#define G5    (2 * NREL * SPLIT)  // 4000 k5 blocks
#define G24   2048                // k2/k4 grid: 8 XCD groups x 256 blocks

typedef _Float16 f16x8 __attribute__((ext_vector_type(8)));
typedef float f32x4 __attribute__((ext_vector_type(4)));

struct alignas(16) h8 { __half2 a, b, c, d; };

// ================= K0: WcT[c][k] = fp16 of (c<128 ? Wh[k][c] : Wt[k][c-128])
__global__ __launch_bounds__(256) void k0_prep(
    const float* __restrict__ Wh, const float* __restrict__ Wt,
    __half* __restrict__ WcT)
{
  const int k = blockIdx.x;
  const int c = threadIdx.x;
  const float v = (c < R_HID) ? Wh[(size_t)k * R_HID + c]
                              : Wt[(size_t)k * R_HID + (c - R_HID)];
  WcT[(size_t)c * E_HID + k] = __float2half(v);
}

// ================= K1: MFMA fp16 GEMM (validated R3+) =======================
__global__ __launch_bounds__(256) void k1_gemm(
    const float* __restrict__ xe, const __half* __restrict__ WcT,
    const float* __restrict__ ah1, const float* __restrict__ ah2,
    const float* __restrict__ at1, const float* __restrict__ at2,
    __half* __restrict__ xhH, __half* __restrict__ xtH,
    float* __restrict__ sh1, float* __restrict__ sh2,
    float* __restrict__ st1, float* __restrict__ st2, int N)
{
  __shared__ __half As[128 * 32];
  __shared__ __half Bs[128 * 32];
  __shared__ float sA[2][128];
  __shared__ float sB[2][128];

  const int tid  = threadIdx.x;
  const int lane = tid & 63;
  const int wid  = tid >> 6;
  const int wr = wid >> 1, wc = wid & 1;
  const int nbm = (N + 127) >> 7;
  const int mb = blockIdx.x % nbm;
  const int cb = blockIdx.x / nbm;
  const int n0 = mb * 128;

  f32x4 acc[4][4];
  #pragma unroll
  for (int m = 0; m < 4; ++m)
    #pragma unroll
    for (int n = 0; n < 4; ++n) acc[m][n] = (f32x4){0.f, 0.f, 0.f, 0.f};

  const int arow = tid >> 1, ah = tid & 1;
  const bool aok = (n0 + arow) < N;
  const float*  xsrc = xe + (size_t)(n0 + arow) * E_HID + ah * 16;
  const __half* bsrc = WcT + ((size_t)(cb * 128 + arow) << 8) + ah * 16;
  __half* Aw = &As[arow * 32 + ah * 16];
  __half* Bw = &Bs[arow * 32 + ah * 16];

  const int fr = lane & 15, fq = lane >> 4;

  for (int kt = 0; kt < 8; ++kt) {
    __syncthreads();
    float4 v0 = make_float4(0,0,0,0), v1 = v0, v2 = v0, v3 = v0;
    if (aok) {
      const float* s = xsrc + kt * 32;
      v0 = *(const float4*)(s);     v1 = *(const float4*)(s + 4);
      v2 = *(const float4*)(s + 8); v3 = *(const float4*)(s + 12);
    }
    h8 p0, p1;
    p0.a = __floats2half2_rn(v0.x, v0.y); p0.b = __floats2half2_rn(v0.z, v0.w);
    p0.c = __floats2half2_rn(v1.x, v1.y); p0.d = __floats2half2_rn(v1.z, v1.w);
    p1.a = __floats2half2_rn(v2.x, v2.y); p1.b = __floats2half2_rn(v2.z, v2.w);
    p1.c = __floats2half2_rn(v3.x, v3.y); p1.d = __floats2half2_rn(v3.z, v3.w);
    *(h8*)(Aw) = p0; *(h8*)(Aw + 8) = p1;
    float4 b0 = *(const float4*)(bsrc + kt * 32);
    float4 b1 = *(const float4*)(bsrc + kt * 32 + 8);
    *(float4*)(Bw) = b0; *(float4*)(Bw + 8) = b1;
    __syncthreads();
    f16x8 aF[4], bF[4];
    #pragma unroll
    for (int m = 0; m < 4; ++m)
      aF[m] = *(const f16x8*)&As[(wr * 64 + m * 16 + fr) * 32 + fq * 8];
    #pragma unroll
    for (int n = 0; n < 4; ++n)
      bF[n] = *(const f16x8*)&Bs[(wc * 64 + n * 16 + fr) * 32 + fq * 8];
    #pragma unroll
    for (int m = 0; m < 4; ++m)
      #pragma unroll
      for (int n = 0; n < 4; ++n)
        acc[m][n] = __builtin_amdgcn_mfma_f32_16x16x32_f16(aF[m], bF[n], acc[m][n], 0, 0, 0);
  }

  __half* dst = (cb == 0) ? xhH : xtH;
  #pragma unroll
  for (int m = 0; m < 4; ++m) {
    const int rl0 = wr * 64 + m * 16 + fq * 4;
    #pragma unroll
    for (int r = 0; r < 4; ++r) {
      const int node = n0 + rl0 + r;
      if (node < N) {
        #pragma unroll
        for (int n = 0; n < 4; ++n)
          dst[(size_t)node * R_HID + wc * 64 + n * 16 + fr] = __float2half(acc[m][n][r]);
      }
    }
  }

  const float* aV1 = (cb == 0) ? ah1 : ah2;
  const float* aV2 = (cb == 0) ? at1 : at2;
  float avA[4], avB[4];
  #pragma unroll
  for (int n = 0; n < 4; ++n) {
    avA[n] = aV1[wc * 64 + n * 16 + fr];
    avB[n] = aV2[wc * 64 + n * 16 + fr];
  }
  #pragma unroll
  for (int m = 0; m < 4; ++m)
    #pragma unroll
    for (int r = 0; r < 4; ++r) {
      float vA = acc[m][0][r]*avA[0] + acc[m][1][r]*avA[1]
               + acc[m][2][r]*avA[2] + acc[m][3][r]*avA[3];
      float vB = acc[m][0][r]*avB[0] + acc[m][1][r]*avB[1]
               + acc[m][2][r]*avB[2] + acc[m][3][r]*avB[3];
      #pragma unroll
      for (int ofs = 1; ofs < 16; ofs <<= 1) {
        vA += __shfl_xor(vA, ofs, 16);
        vB += __shfl_xor(vB, ofs, 16);
      }
      if (fr == 0) {
        const int rl = wr * 64 + m * 16 + fq * 4 + r;
        sA[wc][rl] = vA;
        sB[wc][rl] = vB;
      }
    }
  __syncthreads();
  if (tid < 128 && n0 + tid < N) {
    float* o1 = (cb == 0) ? sh1 : sh2;
    float* o2 = (cb == 0) ? st1 : st2;
    o1[n0 + tid] = sA[0][tid] + sA[1][tid];
    o2[n0 + tid] = sB[0][tid] + sB[1][tid];
  }
}

// ================= K2: XCD-sharded histograms, (rel,chunk) bins =============
// 8 groups x 256 blocks; group g only counts bins with (bin&7)==g -> all
// atomics on a counter stay on one XCD (round-robin bid->XCD).
__global__ __launch_bounds__(256) void k2_hist(
    const int* __restrict__ ei, const int* __restrict__ rel,
    unsigned* __restrict__ cntH, unsigned* __restrict__ cntT, int E)
{
  const int grp = blockIdx.x & 7;
  const int gb  = blockIdx.x >> 3;   // 0..255
  for (int i = gb * 256 + threadIdx.x; i < E; i += 256 * 256) {
    const int r = rel[i];
    const int binH = r * NCH + (ei[i] >> CH_BITS);
    const int binT = r * NCH + (ei[E + i] >> CH_BITS);
    if ((binH & 7) == grp) atomicAdd(cntH + binH, 1u);
    if ((binT & 7) == grp) atomicAdd(cntT + binT, 1u);
  }
}

// ================= K3: carry-scan of 25000 bin totals (one block per list) ==
__global__ __launch_bounds__(1024) void k3_scan(
    const unsigned* __restrict__ cnt, unsigned* __restrict__ offs,
    unsigned* __restrict__ cur)
{
  __shared__ unsigned s[1024];
  const int list = blockIdx.x;
  const unsigned* c = cnt + (size_t)list * NBIN;
  unsigned* o = offs + (size_t)list * (NBIN + 1);
  unsigned* u = cur  + (size_t)list * NBIN;
  const int t = threadIdx.x;
  unsigned carry = 0u;
  for (int base = 0; base < NBIN; base += 1024) {
    const int idx = base + t;
    const unsigned v = (idx < NBIN) ? c[idx] : 0u;
    s[t] = v;
    __syncthreads();
    for (int ofs = 1; ofs < 1024; ofs <<= 1) {
      const unsigned add = (t >= ofs) ? s[t - ofs] : 0u;
      __syncthreads();
      s[t] += add;
      __syncthreads();
    }
    if (idx < NBIN) {
      const unsigned e = carry + s[t] - v;
      o[idx] = e;
      u[idx] = e;
    }
    carry += s[1023];
    __syncthreads();
  }
  if (t == 0) o[NBIN] = carry;
}

// ================= K4: XCD-sharded counting-sort scatter ====================
// Group g writes only bins with (bin&7)==g: every meta cache line is produced
// by ONE XCD, cursor-ordered in time -> full-line writeback (no 8x amp).
__global__ __launch_bounds__(256) void k4_scatter(
    const int* __restrict__ ei, const int* __restrict__ rel,
    const float* __restrict__ sh1, const float* __restrict__ sh2,
    const float* __restrict__ st1, const float* __restrict__ st2,
    unsigned* __restrict__ curH, unsigned* __restrict__ curT,
    uint2* __restrict__ metaH, uint2* __restrict__ metaT, int E)
{
  const int grp = blockIdx.x & 7;
  const int gb  = blockIdx.x >> 3;
  for (int i = gb * 256 + threadIdx.x; i < E; i += 256 * 256) {
    const int h = ei[i], t = ei[E + i], r = rel[i];
    const int binH = r * NCH + (h >> CH_BITS);
    const int binT = r * NCH + (t >> CH_BITS);
    const bool doH = (binH & 7) == grp;
    const bool doT = (binT & 7) == grp;
    if (doH) {
      const float e1 = sh1[h] + sh2[t];
      const float l1 = e1 >= 0.f ? e1 : 0.01f * e1;
      const unsigned p = atomicAdd(curH + binH, 1u);
      metaH[p] = make_uint2((unsigned)h, __float_as_uint(expf(l1)));
    }
    if (doT) {
      const float e2 = st1[h] + st2[t];
      const float l2 = e2 >= 0.f ? e2 : 0.01f * e2;
      const unsigned p = atomicAdd(curT + binT, 1u);
      metaT[p] = make_uint2((unsigned)t, __float_as_uint(expf(l2)));
    }
  }
}

// ================= K5: chunk-phased register gather-reduce (parity split) ===
// block = (list, rel, parity); 4 waves split each chunk-bin; parity groups
// sweep even/odd chunks in phase -> chip-wide active set stays ~2 MB.
__global__ __launch_bounds__(256) void k5_reduce(
    const unsigned* __restrict__ offs,
    const uint2* __restrict__ metaH, const uint2* __restrict__ metaT,
    const __half* __restrict__ xhH, const __half* __restrict__ xtH,
    float* __restrict__ part, float* __restrict__ partS)
{
  __shared__ float accW[4][130];
  __shared__ float accSw[4];
  const int tid  = threadIdx.x;
  const int lane = tid & 63;
  const int wv   = __builtin_amdgcn_readfirstlane(tid >> 6);
  const int bid  = blockIdx.x;
  const int list = bid / (NREL * SPLIT);
  const int rr   = bid % (NREL * SPLIT);
  const int r    = rr >> 1;
  const int par  = rr & 1;

  const unsigned* o    = offs + (size_t)list * (NBIN + 1);
  const uint2*    meta = list ? metaT : metaH;
  const __half*   xsrc = list ? xtH   : xhH;
  const __half*   xl   = xsrc + 2 * lane;

  float a0 = 0.f, a1 = 0.f, sw = 0.f;

  for (int c = par; c < NCH; c += 2) {
    const unsigned s0 = o[r * NCH + c];
    const unsigned s1 = o[r * NCH + c + 1];
    const unsigned len = s1 - s0;
    unsigned p        = s0 + ((len * (unsigned)wv) >> 2);
    const unsigned pe = s0 + ((len * (unsigned)(wv + 1)) >> 2);

    for (; p + 4 <= pe; p += 4) {
      const uint2 m0 = meta[p],     m1 = meta[p + 1];
      const uint2 m2 = meta[p + 2], m3 = meta[p + 3];
      const float2 f0 = __half22float2(*(const __half2*)(xl + ((size_t)m0.x << 7)));
      const float2 f1 = __half22float2(*(const __half2*)(xl + ((size_t)m1.x << 7)));
      const float2 f2 = __half22float2(*(const __half2*)(xl + ((size_t)m2.x << 7)));
      const float2 f3 = __half22float2(*(const __half2*)(xl + ((size_t)m3.x << 7)));
      const float w0 = __uint_as_float(m0.y), w1 = __uint_as_float(m1.y);
      const float w2 = __uint_as_float(m2.y), w3 = __uint_as_float(m3.y);
      a0 += w0 * f0.x; a1 += w0 * f0.y; sw += w0;
      a0 += w1 * f1.x; a1 += w1 * f1.y; sw += w1;
      a0 += w2 * f2.x; a1 += w2 * f2.y; sw += w2;
      a0 += w3 * f3.x; a1 += w3 * f3.y; sw += w3;
    }
    for (; p < pe; ++p) {
      const uint2 m = meta[p];
      const float2 f = __half22float2(*(const __half2*)(xl + ((size_t)m.x << 7)));
      const float w = __uint_as_float(m.y);
      a0 += w * f.x; a1 += w * f.y; sw += w;
    }
  }

  accW[wv][2 * lane]     = a0;
  accW[wv][2 * lane + 1] = a1;
  if (lane == 0) accSw[wv] = sw;
  __syncthreads();
  if (tid < 128) {
    part[(size_t)bid * R_HID + tid] =
        accW[0][tid] + accW[1][tid] + accW[2][tid] + accW[3][tid];
  }
  if (tid == 0)
    partS[bid] = accSw[0] + accSw[1] + accSw[2] + accSw[3];
}

// ================= K6: finalize =============================================
__global__ __launch_bounds__(128) void k6_final(
    const float* __restrict__ part, const float* __restrict__ partS,
    float* __restrict__ out)
{
  const int r = blockIdx.x;
  const int d = threadIdx.x;
  float oh = 0.f, ot = 0.f, s1 = 0.f, s2 = 0.f;
  #pragma unroll
  for (int sp = 0; sp < SPLIT; ++sp) {
    const int pid0 = r * SPLIT + sp;
    const int pid1 = (NREL + r) * SPLIT + sp;
    oh += part[(size_t)pid0 * R_HID + d];
    ot += part[(size_t)pid1 * R_HID + d];
    s1 += partS[pid0];
    s2 += partS[pid1];
  }
  out[r * R_HID + d] = oh / (s1 + EPSF) + ot / (s2 + EPSF);
}

extern "C" void kernel_launch(void* const* d_in, const int* in_sizes, int n_in,
                              void* d_out, int out_size, void* d_ws, size_t ws_size,
                              hipStream_t stream) {
  const float* xe  = (const float*)d_in[0];
  const int*   ei  = (const int*)d_in[1];
  const int*   rel = (const int*)d_in[2];
  const float* Wh  = (const float*)d_in[3];
  const float* Wt  = (const float*)d_in[4];
  const float* ah1 = (const float*)d_in[5];
  const float* ah2 = (const float*)d_in[6];
  const float* at1 = (const float*)d_in[7];
  const float* at2 = (const float*)d_in[8];
  const int N = in_sizes[0] / E_HID;
  const int E = in_sizes[2];

  char* w = (char*)d_ws;
  size_t o = 0;
  auto alloc = [&](size_t bytes) -> void* {
    void* p = w + o;
    o = (o + bytes + 255) & ~(size_t)255;
    return p;
  };
  __half* WcT = (__half*)alloc((size_t)E_HID * E_HID * 2);
  __half* xhH = (__half*)alloc((size_t)N * R_HID * 2);
  __half* xtH = (__half*)alloc((size_t)N * R_HID * 2);
  float* sh1 = (float*)alloc((size_t)N * 4);
  float* sh2 = (float*)alloc((size_t)N * 4);
  float* st1 = (float*)alloc((size_t)N * 4);
  float* st2 = (float*)alloc((size_t)N * 4);
  uint2* metaH = (uint2*)alloc((size_t)E * 8);
  uint2* metaT = (uint2*)alloc((size_t)E * 8);
  unsigned* cur  = (unsigned*)alloc((size_t)2 * NBIN * 4);
  unsigned* offs = (unsigned*)alloc((size_t)2 * (NBIN + 1) * 4);
  float* part  = (float*)alloc((size_t)G5 * R_HID * 4);
  float* partS = (float*)alloc((size_t)G5 * 4);
  const size_t zstart = o;
  unsigned* cnt  = (unsigned*)alloc((size_t)2 * NBIN * 4);
  const size_t zbytes = o - zstart;

  hipMemsetAsync(w + zstart, 0, zbytes, stream);

  const int nbm = (N + 127) >> 7;
  k0_prep<<<E_HID, 256, 0, stream>>>(Wh, Wt, WcT);
  k1_gemm<<<nbm * 2, 256, 0, stream>>>(xe, WcT, ah1, ah2, at1, at2,
                                       xhH, xtH, sh1, sh2, st1, st2, N);
  k2_hist<<<G24, 256, 0, stream>>>(ei, rel, cnt, cnt + NBIN, E);
  k3_scan<<<2, 1024, 0, stream>>>(cnt, offs, cur);
  k4_scatter<<<G24, 256, 0, stream>>>(ei, rel, sh1, sh2, st1, st2,
                                      cur, cur + NBIN, metaH, metaT, E);
  k5_reduce<<<G5, 256, 0, stream>>>(offs, metaH, metaT, xhH, xtH, part, partS);
  k6_final<<<NREL, 128, 0, stream>>>(part, partS, (float*)d_out);
}

// Round 10
// 412.622 us; speedup vs baseline: 1.1529x; 1.1487x over previous
//
#include <hip/hip_runtime.h>
#include <hip/hip_fp16.h>
#include <cstdint>
#include <cstddef>

#define E_HID 256
#define R_HID 128
#define NREL  1000
#define EPSF  1e-16f
#define CHDIV 3136u               // nodes per chunk (50000/3136 -> 16 chunks)
#define NCH   16
#define NBIN  (NREL * NCH)        // 16000 bins per list (rel-major, chunk-minor)
#define NXCD  8
#define G5    (2 * NREL * NXCD)   // 16000 k5 blocks: (list, rel) x chunk-group

typedef _Float16 f16x8 __attribute__((ext_vector_type(8)));
typedef float f32x4 __attribute__((ext_vector_type(4)));

struct alignas(16) h8 { __half2 a, b, c, d; };

// ================= K0: WcT[c][k] = fp16 of (c<128 ? Wh[k][c] : Wt[k][c-128])
__global__ __launch_bounds__(256) void k0_prep(
    const float* __restrict__ Wh, const float* __restrict__ Wt,
    __half* __restrict__ WcT)
{
  const int k = blockIdx.x;
  const int c = threadIdx.x;
  const float v = (c < R_HID) ? Wh[(size_t)k * R_HID + c]
                              : Wt[(size_t)k * R_HID + (c - R_HID)];
  WcT[(size_t)c * E_HID + k] = __float2half(v);
}

// ================= K1: MFMA fp16 GEMM (validated R3+) =======================
__global__ __launch_bounds__(256) void k1_gemm(
    const float* __restrict__ xe, const __half* __restrict__ WcT,
    const float* __restrict__ ah1, const float* __restrict__ ah2,
    const float* __restrict__ at1, const float* __restrict__ at2,
    __half* __restrict__ xhH, __half* __restrict__ xtH,
    float* __restrict__ sh1, float* __restrict__ sh2,
    float* __restrict__ st1, float* __restrict__ st2, int N)
{
  __shared__ __half As[128 * 32];
  __shared__ __half Bs[128 * 32];
  __shared__ float sA[2][128];
  __shared__ float sB[2][128];

  const int tid  = threadIdx.x;
  const int lane = tid & 63;
  const int wid  = tid >> 6;
  const int wr = wid >> 1, wc = wid & 1;
  const int nbm = (N + 127) >> 7;
  const int mb = blockIdx.x % nbm;
  const int cb = blockIdx.x / nbm;
  const int n0 = mb * 128;

  f32x4 acc[4][4];
  #pragma unroll
  for (int m = 0; m < 4; ++m)
    #pragma unroll
    for (int n = 0; n < 4; ++n) acc[m][n] = (f32x4){0.f, 0.f, 0.f, 0.f};

  const int arow = tid >> 1, ah = tid & 1;
  const bool aok = (n0 + arow) < N;
  const float*  xsrc = xe + (size_t)(n0 + arow) * E_HID + ah * 16;
  const __half* bsrc = WcT + ((size_t)(cb * 128 + arow) << 8) + ah * 16;
  __half* Aw = &As[arow * 32 + ah * 16];
  __half* Bw = &Bs[arow * 32 + ah * 16];

  const int fr = lane & 15, fq = lane >> 4;

  for (int kt = 0; kt < 8; ++kt) {
    __syncthreads();
    float4 v0 = make_float4(0,0,0,0), v1 = v0, v2 = v0, v3 = v0;
    if (aok) {
      const float* s = xsrc + kt * 32;
      v0 = *(const float4*)(s);     v1 = *(const float4*)(s + 4);
      v2 = *(const float4*)(s + 8); v3 = *(const float4*)(s + 12);
    }
    h8 p0, p1;
    p0.a = __floats2half2_rn(v0.x, v0.y); p0.b = __floats2half2_rn(v0.z, v0.w);
    p0.c = __floats2half2_rn(v1.x, v1.y); p0.d = __floats2half2_rn(v1.z, v1.w);
    p1.a = __floats2half2_rn(v2.x, v2.y); p1.b = __floats2half2_rn(v2.z, v2.w);
    p1.c = __floats2half2_rn(v3.x, v3.y); p1.d = __floats2half2_rn(v3.z, v3.w);
    *(h8*)(Aw) = p0; *(h8*)(Aw + 8) = p1;
    float4 b0 = *(const float4*)(bsrc + kt * 32);
    float4 b1 = *(const float4*)(bsrc + kt * 32 + 8);
    *(float4*)(Bw) = b0; *(float4*)(Bw + 8) = b1;
    __syncthreads();
    f16x8 aF[4], bF[4];
    #pragma unroll
    for (int m = 0; m < 4; ++m)
      aF[m] = *(const f16x8*)&As[(wr * 64 + m * 16 + fr) * 32 + fq * 8];
    #pragma unroll
    for (int n = 0; n < 4; ++n)
      bF[n] = *(const f16x8*)&Bs[(wc * 64 + n * 16 + fr) * 32 + fq * 8];
    #pragma unroll
    for (int m = 0; m < 4; ++m)
      #pragma unroll
      for (int n = 0; n < 4; ++n)
        acc[m][n] = __builtin_amdgcn_mfma_f32_16x16x32_f16(aF[m], bF[n], acc[m][n], 0, 0, 0);
  }

  __half* dst = (cb == 0) ? xhH : xtH;
  #pragma unroll
  for (int m = 0; m < 4; ++m) {
    const int rl0 = wr * 64 + m * 16 + fq * 4;
    #pragma unroll
    for (int r = 0; r < 4; ++r) {
      const int node = n0 + rl0 + r;
      if (node < N) {
        #pragma unroll
        for (int n = 0; n < 4; ++n)
          dst[(size_t)node * R_HID + wc * 64 + n * 16 + fr] = __float2half(acc[m][n][r]);
      }
    }
  }

  const float* aV1 = (cb == 0) ? ah1 : ah2;
  const float* aV2 = (cb == 0) ? at1 : at2;
  float avA[4], avB[4];
  #pragma unroll
  for (int n = 0; n < 4; ++n) {
    avA[n] = aV1[wc * 64 + n * 16 + fr];
    avB[n] = aV2[wc * 64 + n * 16 + fr];
  }
  #pragma unroll
  for (int m = 0; m < 4; ++m)
    #pragma unroll
    for (int r = 0; r < 4; ++r) {
      float vA = acc[m][0][r]*avA[0] + acc[m][1][r]*avA[1]
               + acc[m][2][r]*avA[2] + acc[m][3][r]*avA[3];
      float vB = acc[m][0][r]*avB[0] + acc[m][1][r]*avB[1]
               + acc[m][2][r]*avB[2] + acc[m][3][r]*avB[3];
      #pragma unroll
      for (int ofs = 1; ofs < 16; ofs <<= 1) {
        vA += __shfl_xor(vA, ofs, 16);
        vB += __shfl_xor(vB, ofs, 16);
      }
      if (fr == 0) {
        const int rl = wr * 64 + m * 16 + fq * 4 + r;
        sA[wc][rl] = vA;
        sB[wc][rl] = vB;
      }
    }
  __syncthreads();
  if (tid < 128 && n0 + tid < N) {
    float* o1 = (cb == 0) ? sh1 : sh2;
    float* o2 = (cb == 0) ? st1 : st2;
    o1[n0 + tid] = sA[0][tid] + sA[1][tid];
    o2[n0 + tid] = sB[0][tid] + sB[1][tid];
  }
}

// ================= K2: global-atomic histograms, (rel,chunk) bins ===========
// 32000 counters total, ~100 hits each: contention path ~20us, no hot spots.
__global__ __launch_bounds__(256) void k2_hist(
    const int* __restrict__ ei, const int* __restrict__ rel,
    unsigned* __restrict__ cntH, unsigned* __restrict__ cntT, int E)
{
  for (int i = blockIdx.x * 256 + threadIdx.x; i < E; i += gridDim.x * 256) {
    const int r = rel[i];
    atomicAdd(cntH + r * NCH + (unsigned)ei[i] / CHDIV, 1u);
    atomicAdd(cntT + r * NCH + (unsigned)ei[E + i] / CHDIV, 1u);
  }
}

// ================= K3: carry-scan of 16000 bin totals (one block per list) ==
__global__ __launch_bounds__(1024) void k3_scan(
    const unsigned* __restrict__ cnt, unsigned* __restrict__ offs,
    unsigned* __restrict__ cur)
{
  __shared__ unsigned s[1024];
  const int list = blockIdx.x;
  const unsigned* c = cnt + (size_t)list * NBIN;
  unsigned* o = offs + (size_t)list * (NBIN + 1);
  unsigned* u = cur  + (size_t)list * NBIN;
  const int t = threadIdx.x;
  unsigned carry = 0u;
  for (int base = 0; base < NBIN; base += 1024) {
    const int idx = base + t;
    const unsigned v = (idx < NBIN) ? c[idx] : 0u;
    s[t] = v;
    __syncthreads();
    for (int ofs = 1; ofs < 1024; ofs <<= 1) {
      const unsigned add = (t >= ofs) ? s[t - ofs] : 0u;
      __syncthreads();
      s[t] += add;
      __syncthreads();
    }
    if (idx < NBIN) {
      const unsigned e = carry + s[t] - v;
      o[idx] = e;
      u[idx] = e;
    }
    carry += s[1023];
    __syncthreads();
  }
  if (t == 0) o[NBIN] = carry;
}

// ================= K4: counting-sort scatter, global cursors ================
// 16000 bins/list, ~100 edges/bin -> cache lines fill fast (~8% of pass),
// near-zero write amplification (R3-proven regime). meta = {node, w(f32)}.
__global__ __launch_bounds__(256) void k4_scatter(
    const int* __restrict__ ei, const int* __restrict__ rel,
    const float* __restrict__ sh1, const float* __restrict__ sh2,
    const float* __restrict__ st1, const float* __restrict__ st2,
    unsigned* __restrict__ curH, unsigned* __restrict__ curT,
    uint2* __restrict__ metaH, uint2* __restrict__ metaT, int E)
{
  for (int i = blockIdx.x * 256 + threadIdx.x; i < E; i += gridDim.x * 256) {
    const int h = ei[i], t = ei[E + i], r = rel[i];
    const float e1 = sh1[h] + sh2[t];
    const float e2 = st1[h] + st2[t];
    const float l1 = e1 >= 0.f ? e1 : 0.01f * e1;
    const float l2 = e2 >= 0.f ? e2 : 0.01f * e2;
    const float w1 = expf(l1);
    const float w2 = expf(l2);
    const unsigned pH = atomicAdd(curH + r * NCH + (unsigned)h / CHDIV, 1u);
    metaH[pH] = make_uint2((unsigned)h, __float_as_uint(w1));
    const unsigned pT = atomicAdd(curT + r * NCH + (unsigned)t / CHDIV, 1u);
    metaT[pT] = make_uint2((unsigned)t, __float_as_uint(w2));
  }
}

// ================= K5: XCD-partitioned chunk-phased gather-reduce ===========
// bid = j*8 + g: group g (-> XCD g under round-robin) owns chunks {g, g+8}
// for (list,rel) = j. Each XCD's L2 only ever touches its own ~3.1 MB of the
// tables -> table refill drops from 8x25.6 MB to 25.6 MB chip-wide.
__global__ __launch_bounds__(256) void k5_reduce(
    const unsigned* __restrict__ offs,
    const uint2* __restrict__ metaH, const uint2* __restrict__ metaT,
    const __half* __restrict__ xhH, const __half* __restrict__ xtH,
    float* __restrict__ part, float* __restrict__ partS)
{
  __shared__ float accW[4][130];
  __shared__ float accSw[4];
  const int tid  = threadIdx.x;
  const int lane = tid & 63;
  const int wv   = __builtin_amdgcn_readfirstlane(tid >> 6);
  const int bid  = blockIdx.x;
  const int g    = bid & 7;
  const int j    = bid >> 3;        // 0..1999
  const int list = j & 1;
  const int r    = j >> 1;

  const unsigned* o    = offs + (size_t)list * (NBIN + 1);
  const uint2*    meta = list ? metaT : metaH;
  const __half*   xsrc = list ? xtH   : xhH;
  const __half*   xl   = xsrc + 2 * lane;

  float a0 = 0.f, a1 = 0.f, sw = 0.f;

  for (int c = g; c < NCH; c += 8) {
    const unsigned s0 = o[r * NCH + c];
    const unsigned s1 = o[r * NCH + c + 1];
    const unsigned len = s1 - s0;
    unsigned p        = s0 + ((len * (unsigned)wv) >> 2);
    const unsigned pe = s0 + ((len * (unsigned)(wv + 1)) >> 2);

    for (; p + 4 <= pe; p += 4) {
      const uint2 m0 = meta[p],     m1 = meta[p + 1];
      const uint2 m2 = meta[p + 2], m3 = meta[p + 3];
      const float2 f0 = __half22float2(*(const __half2*)(xl + ((size_t)m0.x << 7)));
      const float2 f1 = __half22float2(*(const __half2*)(xl + ((size_t)m1.x << 7)));
      const float2 f2 = __half22float2(*(const __half2*)(xl + ((size_t)m2.x << 7)));
      const float2 f3 = __half22float2(*(const __half2*)(xl + ((size_t)m3.x << 7)));
      const float w0 = __uint_as_float(m0.y), w1 = __uint_as_float(m1.y);
      const float w2 = __uint_as_float(m2.y), w3 = __uint_as_float(m3.y);
      a0 += w0 * f0.x; a1 += w0 * f0.y; sw += w0;
      a0 += w1 * f1.x; a1 += w1 * f1.y; sw += w1;
      a0 += w2 * f2.x; a1 += w2 * f2.y; sw += w2;
      a0 += w3 * f3.x; a1 += w3 * f3.y; sw += w3;
    }
    for (; p < pe; ++p) {
      const uint2 m = meta[p];
      const float2 f = __half22float2(*(const __half2*)(xl + ((size_t)m.x << 7)));
      const float w = __uint_as_float(m.y);
      a0 += w * f.x; a1 += w * f.y; sw += w;
    }
  }

  accW[wv][2 * lane]     = a0;
  accW[wv][2 * lane + 1] = a1;
  if (lane == 0) accSw[wv] = sw;
  __syncthreads();
  if (tid < 128) {
    part[(size_t)bid * R_HID + tid] =
        accW[0][tid] + accW[1][tid] + accW[2][tid] + accW[3][tid];
  }
  if (tid == 0)
    partS[bid] = accSw[0] + accSw[1] + accSw[2] + accSw[3];
}

// ================= K6: reduce 8 chunk-group partials, finalize ==============
__global__ __launch_bounds__(128) void k6_final(
    const float* __restrict__ part, const float* __restrict__ partS,
    float* __restrict__ out)
{
  const int r = blockIdx.x;
  const int d = threadIdx.x;
  float oh = 0.f, ot = 0.f, s1 = 0.f, s2 = 0.f;
  const int bh = (r * 2 + 0) * 8;
  const int bt = (r * 2 + 1) * 8;
  #pragma unroll
  for (int g = 0; g < NXCD; ++g) {
    oh += part[(size_t)(bh + g) * R_HID + d];
    ot += part[(size_t)(bt + g) * R_HID + d];
    s1 += partS[bh + g];
    s2 += partS[bt + g];
  }
  out[r * R_HID + d] = oh / (s1 + EPSF) + ot / (s2 + EPSF);
}

extern "C" void kernel_launch(void* const* d_in, const int* in_sizes, int n_in,
                              void* d_out, int out_size, void* d_ws, size_t ws_size,
                              hipStream_t stream) {
  const float* xe  = (const float*)d_in[0];
  const int*   ei  = (const int*)d_in[1];
  const int*   rel = (const int*)d_in[2];
  const float* Wh  = (const float*)d_in[3];
  const float* Wt  = (const float*)d_in[4];
  const float* ah1 = (const float*)d_in[5];
  const float* ah2 = (const float*)d_in[6];
  const float* at1 = (const float*)d_in[7];
  const float* at2 = (const float*)d_in[8];
  const int N = in_sizes[0] / E_HID;
  const int E = in_sizes[2];

  char* w = (char*)d_ws;
  size_t o = 0;
  auto alloc = [&](size_t bytes) -> void* {
    void* p = w + o;
    o = (o + bytes + 255) & ~(size_t)255;
    return p;
  };
  __half* WcT = (__half*)alloc((size_t)E_HID * E_HID * 2);
  __half* xhH = (__half*)alloc((size_t)N * R_HID * 2);
  __half* xtH = (__half*)alloc((size_t)N * R_HID * 2);
  float* sh1 = (float*)alloc((size_t)N * 4);
  float* sh2 = (float*)alloc((size_t)N * 4);
  float* st1 = (float*)alloc((size_t)N * 4);
  float* st2 = (float*)alloc((size_t)N * 4);
  uint2* metaH = (uint2*)alloc((size_t)E * 8);
  uint2* metaT = (uint2*)alloc((size_t)E * 8);
  unsigned* cur  = (unsigned*)alloc((size_t)2 * NBIN * 4);
  unsigned* offs = (unsigned*)alloc((size_t)2 * (NBIN + 1) * 4);
  float* part  = (float*)alloc((size_t)G5 * R_HID * 4);
  float* partS = (float*)alloc((size_t)G5 * 4);
  const size_t zstart = o;
  unsigned* cnt  = (unsigned*)alloc((size_t)2 * NBIN * 4);
  const size_t zbytes = o - zstart;

  hipMemsetAsync(w + zstart, 0, zbytes, stream);

  const int nbm = (N + 127) >> 7;
  k0_prep<<<E_HID, 256, 0, stream>>>(Wh, Wt, WcT);
  k1_gemm<<<nbm * 2, 256, 0, stream>>>(xe, WcT, ah1, ah2, at1, at2,
                                       xhH, xtH, sh1, sh2, st1, st2, N);
  k2_hist<<<1024, 256, 0, stream>>>(ei, rel, cnt, cnt + NBIN, E);
  k3_scan<<<2, 1024, 0, stream>>>(cnt, offs, cur);
  k4_scatter<<<1024, 256, 0, stream>>>(ei, rel, sh1, sh2, st1, st2,
                                       cur, cur + NBIN, metaH, metaT, E);
  k5_reduce<<<G5, 256, 0, stream>>>(offs, metaH, metaT, xhH, xtH, part, partS);
  k6_final<<<NREL, 128, 0, stream>>>(part, partS, (float*)d_out);
}

// Round 11
// 375.195 us; speedup vs baseline: 1.2679x; 1.0998x over previous
//
#include <hip/hip_runtime.h>
#include <hip/hip_fp16.h>
#include <cstdint>
#include <cstddef>

#define E_HID 256
#define R_HID 128
#define NREL  1000
#define EPSF  1e-16f
#define CHDIV 6250u               // nodes per chunk -> 8 chunks
#define NCH   8
#define NBIN  (NREL * NCH)        // 8000 bins per list (rel-major, chunk-minor)
#define G5    (2 * NREL)          // k5 blocks: one per (list, rel)  [R7-proven]
#define TILE  4096                // edges per k4 block
#define NT4   ((1600000 + TILE - 1) / TILE)   // 391 tiles (E is fixed)

typedef _Float16 f16x8 __attribute__((ext_vector_type(8)));
typedef float f32x4 __attribute__((ext_vector_type(4)));

struct alignas(16) h8 { __half2 a, b, c, d; };

// ================= K0: WcT[c][k] = fp16 of (c<128 ? Wh[k][c] : Wt[k][c-128])
__global__ __launch_bounds__(256) void k0_prep(
    const float* __restrict__ Wh, const float* __restrict__ Wt,
    __half* __restrict__ WcT)
{
  const int k = blockIdx.x;
  const int c = threadIdx.x;
  const float v = (c < R_HID) ? Wh[(size_t)k * R_HID + c]
                              : Wt[(size_t)k * R_HID + (c - R_HID)];
  WcT[(size_t)c * E_HID + k] = __float2half(v);
}

// ================= K1: MFMA fp16 GEMM (validated R3+) =======================
__global__ __launch_bounds__(256) void k1_gemm(
    const float* __restrict__ xe, const __half* __restrict__ WcT,
    const float* __restrict__ ah1, const float* __restrict__ ah2,
    const float* __restrict__ at1, const float* __restrict__ at2,
    __half* __restrict__ xhH, __half* __restrict__ xtH,
    float* __restrict__ sh1, float* __restrict__ sh2,
    float* __restrict__ st1, float* __restrict__ st2, int N)
{
  __shared__ __half As[128 * 32];
  __shared__ __half Bs[128 * 32];
  __shared__ float sA[2][128];
  __shared__ float sB[2][128];

  const int tid  = threadIdx.x;
  const int lane = tid & 63;
  const int wid  = tid >> 6;
  const int wr = wid >> 1, wc = wid & 1;
  const int nbm = (N + 127) >> 7;
  const int mb = blockIdx.x % nbm;
  const int cb = blockIdx.x / nbm;
  const int n0 = mb * 128;

  f32x4 acc[4][4];
  #pragma unroll
  for (int m = 0; m < 4; ++m)
    #pragma unroll
    for (int n = 0; n < 4; ++n) acc[m][n] = (f32x4){0.f, 0.f, 0.f, 0.f};

  const int arow = tid >> 1, ah = tid & 1;
  const bool aok = (n0 + arow) < N;
  const float*  xsrc = xe + (size_t)(n0 + arow) * E_HID + ah * 16;
  const __half* bsrc = WcT + ((size_t)(cb * 128 + arow) << 8) + ah * 16;
  __half* Aw = &As[arow * 32 + ah * 16];
  __half* Bw = &Bs[arow * 32 + ah * 16];

  const int fr = lane & 15, fq = lane >> 4;

  for (int kt = 0; kt < 8; ++kt) {
    __syncthreads();
    float4 v0 = make_float4(0,0,0,0), v1 = v0, v2 = v0, v3 = v0;
    if (aok) {
      const float* s = xsrc + kt * 32;
      v0 = *(const float4*)(s);     v1 = *(const float4*)(s + 4);
      v2 = *(const float4*)(s + 8); v3 = *(const float4*)(s + 12);
    }
    h8 p0, p1;
    p0.a = __floats2half2_rn(v0.x, v0.y); p0.b = __floats2half2_rn(v0.z, v0.w);
    p0.c = __floats2half2_rn(v1.x, v1.y); p0.d = __floats2half2_rn(v1.z, v1.w);
    p1.a = __floats2half2_rn(v2.x, v2.y); p1.b = __floats2half2_rn(v2.z, v2.w);
    p1.c = __floats2half2_rn(v3.x, v3.y); p1.d = __floats2half2_rn(v3.z, v3.w);
    *(h8*)(Aw) = p0; *(h8*)(Aw + 8) = p1;
    float4 b0 = *(const float4*)(bsrc + kt * 32);
    float4 b1 = *(const float4*)(bsrc + kt * 32 + 8);
    *(float4*)(Bw) = b0; *(float4*)(Bw + 8) = b1;
    __syncthreads();
    f16x8 aF[4], bF[4];
    #pragma unroll
    for (int m = 0; m < 4; ++m)
      aF[m] = *(const f16x8*)&As[(wr * 64 + m * 16 + fr) * 32 + fq * 8];
    #pragma unroll
    for (int n = 0; n < 4; ++n)
      bF[n] = *(const f16x8*)&Bs[(wc * 64 + n * 16 + fr) * 32 + fq * 8];
    #pragma unroll
    for (int m = 0; m < 4; ++m)
      #pragma unroll
      for (int n = 0; n < 4; ++n)
        acc[m][n] = __builtin_amdgcn_mfma_f32_16x16x32_f16(aF[m], bF[n], acc[m][n], 0, 0, 0);
  }

  __half* dst = (cb == 0) ? xhH : xtH;
  #pragma unroll
  for (int m = 0; m < 4; ++m) {
    const int rl0 = wr * 64 + m * 16 + fq * 4;
    #pragma unroll
    for (int r = 0; r < 4; ++r) {
      const int node = n0 + rl0 + r;
      if (node < N) {
        #pragma unroll
        for (int n = 0; n < 4; ++n)
          dst[(size_t)node * R_HID + wc * 64 + n * 16 + fr] = __float2half(acc[m][n][r]);
      }
    }
  }

  const float* aV1 = (cb == 0) ? ah1 : ah2;
  const float* aV2 = (cb == 0) ? at1 : at2;
  float avA[4], avB[4];
  #pragma unroll
  for (int n = 0; n < 4; ++n) {
    avA[n] = aV1[wc * 64 + n * 16 + fr];
    avB[n] = aV2[wc * 64 + n * 16 + fr];
  }
  #pragma unroll
  for (int m = 0; m < 4; ++m)
    #pragma unroll
    for (int r = 0; r < 4; ++r) {
      float vA = acc[m][0][r]*avA[0] + acc[m][1][r]*avA[1]
               + acc[m][2][r]*avA[2] + acc[m][3][r]*avA[3];
      float vB = acc[m][0][r]*avB[0] + acc[m][1][r]*avB[1]
               + acc[m][2][r]*avB[2] + acc[m][3][r]*avB[3];
      #pragma unroll
      for (int ofs = 1; ofs < 16; ofs <<= 1) {
        vA += __shfl_xor(vA, ofs, 16);
        vB += __shfl_xor(vB, ofs, 16);
      }
      if (fr == 0) {
        const int rl = wr * 64 + m * 16 + fq * 4 + r;
        sA[wc][rl] = vA;
        sB[wc][rl] = vB;
      }
    }
  __syncthreads();
  if (tid < 128 && n0 + tid < N) {
    float* o1 = (cb == 0) ? sh1 : sh2;
    float* o2 = (cb == 0) ? st1 : st2;
    o1[n0 + tid] = sA[0][tid] + sA[1][tid];
    o2[n0 + tid] = sB[0][tid] + sB[1][tid];
  }
}

// ================= K2: global-atomic histograms, (rel,chunk) bins ===========
__global__ __launch_bounds__(256) void k2_hist(
    const int* __restrict__ ei, const int* __restrict__ rel,
    unsigned* __restrict__ cntH, unsigned* __restrict__ cntT, int E)
{
  for (int i = blockIdx.x * 256 + threadIdx.x; i < E; i += gridDim.x * 256) {
    const int r = rel[i];
    atomicAdd(cntH + r * NCH + (unsigned)ei[i] / CHDIV, 1u);
    atomicAdd(cntT + r * NCH + (unsigned)ei[E + i] / CHDIV, 1u);
  }
}

// ================= K3: carry-scan of 8000 bin totals (one block per list) ===
__global__ __launch_bounds__(1024) void k3_scan(
    const unsigned* __restrict__ cnt, unsigned* __restrict__ offs,
    unsigned* __restrict__ cur)
{
  __shared__ unsigned s[1024];
  const int list = blockIdx.x;
  const unsigned* c = cnt + (size_t)list * NBIN;
  unsigned* o = offs + (size_t)list * (NBIN + 1);
  unsigned* u = cur  + (size_t)list * NBIN;
  const int t = threadIdx.x;
  unsigned carry = 0u;
  for (int base = 0; base < NBIN; base += 1024) {
    const int idx = base + t;
    const unsigned v = (idx < NBIN) ? c[idx] : 0u;
    s[t] = v;
    __syncthreads();
    for (int ofs = 1; ofs < 1024; ofs <<= 1) {
      const unsigned add = (t >= ofs) ? s[t - ofs] : 0u;
      __syncthreads();
      s[t] += add;
      __syncthreads();
    }
    if (idx < NBIN) {
      const unsigned e = carry + s[t] - v;
      o[idx] = e;
      u[idx] = e;
    }
    carry += s[1023];
    __syncthreads();
  }
  if (t == 0) o[NBIN] = carry;
}

// ================= K4: block-aggregated counting scatter ====================
// One block = one list x one 4096-edge tile. LDS tile-histogram -> one global
// cursor atomic per NONZERO bin (range reservation) -> LDS-ranked writes.
// Every meta cache line is written by a single block in a tight window ->
// full-line writeback, no 8x amplification.
__global__ __launch_bounds__(256) void k4_scatter(
    const int* __restrict__ ei, const int* __restrict__ rel,
    const float* __restrict__ sh1, const float* __restrict__ sh2,
    const float* __restrict__ st1, const float* __restrict__ st2,
    unsigned* __restrict__ cur,
    uint2* __restrict__ metaH, uint2* __restrict__ metaT, int E)
{
  __shared__ unsigned cnt[NBIN];   // 32 KB: counts, then bases (in-place)
  const int tid  = threadIdx.x;
  const int list = blockIdx.x & 1;
  const int tb   = blockIdx.x >> 1;
  const int i0   = tb * TILE;

  for (int j = tid; j < NBIN; j += 256) cnt[j] = 0u;
  __syncthreads();

  const int* nodes = ei + (size_t)list * E;
  // Pass A: tile histogram
  #pragma unroll
  for (int k = 0; k < TILE / 256; ++k) {
    const int i = i0 + k * 256 + tid;
    if (i < E)
      atomicAdd(&cnt[rel[i] * NCH + (unsigned)nodes[i] / CHDIV], 1u);
  }
  __syncthreads();
  // Reserve: one global atomic per nonzero bin; counts -> bases in-place
  unsigned* mycur = cur + (size_t)list * NBIN;
  for (int j = tid; j < NBIN; j += 256) {
    const unsigned c = cnt[j];
    if (c) cnt[j] = atomicAdd(mycur + j, c);
  }
  __syncthreads();
  // Pass B: compute w, rank via LDS atomic on base, write meta
  uint2* meta = list ? metaT : metaH;
  const float* sA = list ? st1 : sh1;
  const float* sB = list ? st2 : sh2;
  #pragma unroll
  for (int k = 0; k < TILE / 256; ++k) {
    const int i = i0 + k * 256 + tid;
    if (i < E) {
      const int h = ei[i], t = ei[E + i], r = rel[i];
      const int nd = list ? t : h;
      const float e = sA[h] + sB[t];
      const float l = e >= 0.f ? e : 0.01f * e;
      const float w = expf(l);
      const unsigned pos = atomicAdd(&cnt[r * NCH + (unsigned)nd / CHDIV], 1u);
      meta[pos] = make_uint2((unsigned)nd, __float_as_uint(w));
    }
  }
}

// ================= K5: chunk-phased register gather-reduce (R7-proven) ======
// block = (list, rel); 4 waves split each chunk-bin's edges; ALL blocks sweep
// chunks 0..7 in the same order -> chip-wide active frontier ~few MB.
__global__ __launch_bounds__(256) void k5_reduce(
    const unsigned* __restrict__ offs,
    const uint2* __restrict__ metaH, const uint2* __restrict__ metaT,
    const __half* __restrict__ xhH, const __half* __restrict__ xtH,
    float* __restrict__ part, float* __restrict__ partS)
{
  __shared__ float accW[4][130];
  __shared__ float accSw[4];
  const int tid  = threadIdx.x;
  const int lane = tid & 63;
  const int wv   = __builtin_amdgcn_readfirstlane(tid >> 6);
  const int bid  = blockIdx.x;
  const int list = bid / NREL;
  const int r    = bid % NREL;

  const unsigned* o    = offs + (size_t)list * (NBIN + 1);
  const uint2*    meta = list ? metaT : metaH;
  const __half*   xsrc = list ? xtH   : xhH;
  const __half*   xl   = xsrc + 2 * lane;

  float a0 = 0.f, a1 = 0.f, sw = 0.f;

  for (int c = 0; c < NCH; ++c) {
    const unsigned s0 = o[r * NCH + c];
    const unsigned s1 = o[r * NCH + c + 1];
    const unsigned len = s1 - s0;
    unsigned p        = s0 + ((len * (unsigned)wv) >> 2);
    const unsigned pe = s0 + ((len * (unsigned)(wv + 1)) >> 2);

    for (; p + 4 <= pe; p += 4) {
      const uint2 m0 = meta[p],     m1 = meta[p + 1];
      const uint2 m2 = meta[p + 2], m3 = meta[p + 3];
      const float2 f0 = __half22float2(*(const __half2*)(xl + ((size_t)m0.x << 7)));
      const float2 f1 = __half22float2(*(const __half2*)(xl + ((size_t)m1.x << 7)));
      const float2 f2 = __half22float2(*(const __half2*)(xl + ((size_t)m2.x << 7)));
      const float2 f3 = __half22float2(*(const __half2*)(xl + ((size_t)m3.x << 7)));
      const float w0 = __uint_as_float(m0.y), w1 = __uint_as_float(m1.y);
      const float w2 = __uint_as_float(m2.y), w3 = __uint_as_float(m3.y);
      a0 += w0 * f0.x; a1 += w0 * f0.y; sw += w0;
      a0 += w1 * f1.x; a1 += w1 * f1.y; sw += w1;
      a0 += w2 * f2.x; a1 += w2 * f2.y; sw += w2;
      a0 += w3 * f3.x; a1 += w3 * f3.y; sw += w3;
    }
    for (; p < pe; ++p) {
      const uint2 m = meta[p];
      const float2 f = __half22float2(*(const __half2*)(xl + ((size_t)m.x << 7)));
      const float w = __uint_as_float(m.y);
      a0 += w * f.x; a1 += w * f.y; sw += w;
    }
  }

  accW[wv][2 * lane]     = a0;
  accW[wv][2 * lane + 1] = a1;
  if (lane == 0) accSw[wv] = sw;
  __syncthreads();
  if (tid < 128) {
    part[(size_t)bid * R_HID + tid] =
        accW[0][tid] + accW[1][tid] + accW[2][tid] + accW[3][tid];
  }
  if (tid == 0)
    partS[bid] = accSw[0] + accSw[1] + accSw[2] + accSw[3];
}

// ================= K6: finalize =============================================
__global__ __launch_bounds__(128) void k6_final(
    const float* __restrict__ part, const float* __restrict__ partS,
    float* __restrict__ out)
{
  const int r = blockIdx.x;
  const int d = threadIdx.x;
  const float oh = part[(size_t)r * R_HID + d];
  const float ot = part[(size_t)(NREL + r) * R_HID + d];
  out[r * R_HID + d] = oh / (partS[r] + EPSF) + ot / (partS[NREL + r] + EPSF);
}

extern "C" void kernel_launch(void* const* d_in, const int* in_sizes, int n_in,
                              void* d_out, int out_size, void* d_ws, size_t ws_size,
                              hipStream_t stream) {
  const float* xe  = (const float*)d_in[0];
  const int*   ei  = (const int*)d_in[1];
  const int*   rel = (const int*)d_in[2];
  const float* Wh  = (const float*)d_in[3];
  const float* Wt  = (const float*)d_in[4];
  const float* ah1 = (const float*)d_in[5];
  const float* ah2 = (const float*)d_in[6];
  const float* at1 = (const float*)d_in[7];
  const float* at2 = (const float*)d_in[8];
  const int N = in_sizes[0] / E_HID;
  const int E = in_sizes[2];

  char* w = (char*)d_ws;
  size_t o = 0;
  auto alloc = [&](size_t bytes) -> void* {
    void* p = w + o;
    o = (o + bytes + 255) & ~(size_t)255;
    return p;
  };
  __half* WcT = (__half*)alloc((size_t)E_HID * E_HID * 2);
  __half* xhH = (__half*)alloc((size_t)N * R_HID * 2);
  __half* xtH = (__half*)alloc((size_t)N * R_HID * 2);
  float* sh1 = (float*)alloc((size_t)N * 4);
  float* sh2 = (float*)alloc((size_t)N * 4);
  float* st1 = (float*)alloc((size_t)N * 4);
  float* st2 = (float*)alloc((size_t)N * 4);
  uint2* metaH = (uint2*)alloc((size_t)E * 8);
  uint2* metaT = (uint2*)alloc((size_t)E * 8);
  unsigned* cur  = (unsigned*)alloc((size_t)2 * NBIN * 4);
  unsigned* offs = (unsigned*)alloc((size_t)2 * (NBIN + 1) * 4);
  float* part  = (float*)alloc((size_t)G5 * R_HID * 4);
  float* partS = (float*)alloc((size_t)G5 * 4);
  const size_t zstart = o;
  unsigned* cnt  = (unsigned*)alloc((size_t)2 * NBIN * 4);
  const size_t zbytes = o - zstart;

  hipMemsetAsync(w + zstart, 0, zbytes, stream);

  const int nbm = (N + 127) >> 7;
  k0_prep<<<E_HID, 256, 0, stream>>>(Wh, Wt, WcT);
  k1_gemm<<<nbm * 2, 256, 0, stream>>>(xe, WcT, ah1, ah2, at1, at2,
                                       xhH, xtH, sh1, sh2, st1, st2, N);
  k2_hist<<<1024, 256, 0, stream>>>(ei, rel, cnt, cnt + NBIN, E);
  k3_scan<<<2, 1024, 0, stream>>>(cnt, offs, cur);
  const int nt4 = (E + TILE - 1) / TILE;
  k4_scatter<<<2 * nt4, 256, 0, stream>>>(ei, rel, sh1, sh2, st1, st2,
                                          cur, metaH, metaT, E);
  k5_reduce<<<G5, 256, 0, stream>>>(offs, metaH, metaT, xhH, xtH, part, partS);
  k6_final<<<NREL, 128, 0, stream>>>(part, partS, (float*)d_out);
}